// Round 12
// baseline (78.828 us; speedup 1.0000x reference)
//
#include <hip/hip_runtime.h>
#include <hip/hip_bf16.h>
#include <math.h>

#define TT 577          // real tokens per n
#define TP 640          // padded tokens per n
#define CCH 768         // channels
#define KR 64           // regions
#define NB 64           // batch
#define LSTR 136        // LDS row stride in ushorts (272 B = 17 x 16B)

typedef __attribute__((ext_vector_type(8))) short bf16x8;
typedef __attribute__((ext_vector_type(8))) unsigned short ushort8;
typedef __attribute__((ext_vector_type(4))) float f32x4;

static constexpr float EPSF = 1e-12f;

// float -> bf16 bits via HW conversion (RNE)
static __device__ inline unsigned short f2bf(float f) {
    return __bfloat16_as_ushort(__float2bfloat16(f));
}
static __device__ inline float bf2f(unsigned short b) {
    union { unsigned int u; float f; } v; v.u = ((unsigned int)b) << 16;
    return v.f;
}

// ---------------------------------------------------------------------------
// Kernel 0: one-time prep. (a) conv_w fp32 -> bf16 ws_w[64][768];
// (b) zero ws_a row tails t in [592,640). Grid 24 x 256.
// ---------------------------------------------------------------------------
__global__ __launch_bounds__(256) void k_prep(
    const float* __restrict__ conv_w,
    unsigned short* __restrict__ ws_w,
    unsigned short* __restrict__ ws_a)
{
    const int g = blockIdx.x * 256 + threadIdx.x;   // [0, 6144)
    if (g < 6144) {
        const float* s = conv_w + (size_t)g * 8;
        float4 v0 = *reinterpret_cast<const float4*>(s);
        float4 v1 = *reinterpret_cast<const float4*>(s + 4);
        ushort8 o;
        o[0]=f2bf(v0.x); o[1]=f2bf(v0.y); o[2]=f2bf(v0.z); o[3]=f2bf(v0.w);
        o[4]=f2bf(v1.x); o[5]=f2bf(v1.y); o[6]=f2bf(v1.z); o[7]=f2bf(v1.w);
        *reinterpret_cast<ushort8*>(ws_w + (size_t)g * 8) = o;
    }
    if (g < 4096) {
        unsigned short* d = ws_a + (size_t)g * TP + 592;
        ushort8 z = {0,0,0,0,0,0,0,0};
        #pragma unroll
        for (int i = 0; i < 6; ++i)
            *reinterpret_cast<ushort8*>(d + i * 8) = z;
    }
}

// ---------------------------------------------------------------------------
// Kernel 1 v6: GEMM1 + norm + softmax + a' transpose + partial asum.
// Grid: 64 n x 10 t-blocks of 64 tokens; 256 thr = 4 waves x 16 tokens.
// DENSE staging (lane i <-> consecutive 16 B; every cache line 100% used):
//   G chunk [64t x 128c] fp32: f=it*256+tid, t=f>>5, c4=f&31 -> per instr
//   two full 512-B row segments (8 fully-used 128-B lines).
//   W chunk [64kr x 128c] bf16 (prepped): kr=f>>4, c8=f&15 -> 4x256-B segs.
// G double-buffered, W single-buffered (LDS 52.2 KB -> 3 blocks/CU).
// Per chunk: issue 12 dense loads early -> 4 KSTEPs -> barrier -> write ->
// barrier. Attacks the per-CU line-slot starvation that capped R6-R11.
// ---------------------------------------------------------------------------
__global__ __launch_bounds__(256, 3) void k_logits(
    const float* __restrict__ grids,
    const unsigned short* __restrict__ ws_w,
    const float* __restrict__ conv_b,
    unsigned short* __restrict__ ws_a,
    float* __restrict__ ws_asum)
{
    __shared__ __align__(16) unsigned short Gs[2][64 * LSTR];  // 34.8 KB
    __shared__ __align__(16) unsigned short Ws[64 * LSTR];     // 17.4 KB
    __shared__ float asum_lds[4][64];                          // 1 KB

    const int tid  = threadIdx.x;
    const int lane = tid & 63;
    const int w    = tid >> 6;
    const int n    = blockIdx.x / 10;
    const int tb   = (blockIdx.x - n * 10) << 6;
    const int t0w  = tb + (w << 4);

    const int lr = lane & 15;
    const int lg = lane >> 4;

    const float* gbase = grids + (size_t)n * TT * CCH;

    float4  ga[8];
    ushort8 wa[4];

    #define GLOAD(c0_)                                                        \
        { _Pragma("unroll")                                                   \
          for (int it = 0; it < 8; ++it) {                                    \
              const int f = (it << 8) + tid;                                  \
              const int t = f >> 5, c4 = f & 31;                              \
              ga[it] = (tb + t < TT)                                          \
                  ? *reinterpret_cast<const float4*>(                         \
                        gbase + (size_t)(tb + t) * CCH + (c0_) + (c4 << 2))   \
                  : make_float4(0.f, 0.f, 0.f, 0.f);                          \
          } }

    #define GWRITE(buf_)                                                      \
        { _Pragma("unroll")                                                   \
          for (int it = 0; it < 8; ++it) {                                    \
              const int f = (it << 8) + tid;                                  \
              const int t = f >> 5, c4 = f & 31;                              \
              unsigned short o4[4] = { f2bf(ga[it].x), f2bf(ga[it].y),        \
                                       f2bf(ga[it].z), f2bf(ga[it].w) };      \
              *reinterpret_cast<uint2*>(&Gs[buf_][t * LSTR + (c4 << 2)]) =    \
                  *reinterpret_cast<const uint2*>(o4);                        \
          } }

    #define WLOADD(c0_)                                                       \
        { _Pragma("unroll")                                                   \
          for (int it = 0; it < 4; ++it) {                                    \
              const int f = (it << 8) + tid;                                  \
              const int kr = f >> 4, c8 = f & 15;                             \
              wa[it] = *reinterpret_cast<const ushort8*>(                     \
                  ws_w + (size_t)kr * CCH + (c0_) + (c8 << 3));               \
          } }

    #define WWRITED()                                                         \
        { _Pragma("unroll")                                                   \
          for (int it = 0; it < 4; ++it) {                                    \
              const int f = (it << 8) + tid;                                  \
              const int kr = f >> 4, c8 = f & 15;                             \
              *reinterpret_cast<ushort8*>(&Ws[kr * LSTR + (c8 << 3)]) = wa[it]; \
          } }

    f32x4 acc[4] = {};
    float ss = 0.f;

    GLOAD(0) WLOADD(0)
    GWRITE(0) WWRITED()
    __syncthreads();

    for (int ch = 0; ch < 6; ++ch) {
        if (ch < 5) { GLOAD((ch + 1) << 7) WLOADD((ch + 1) << 7) }

        const unsigned short* Gb = &Gs[ch & 1][0];
        #pragma unroll
        for (int s = 0; s < 4; ++s) {
            const int cl = (s << 5) + (lg << 3);
            bf16x8 af = *reinterpret_cast<const bf16x8*>(
                &Gb[((w << 4) + lr) * LSTR + cl]);
            #pragma unroll
            for (int j = 0; j < 8; ++j) {
                const float v = bf2f(((unsigned short*)&af)[j]);
                ss = fmaf(v, v, ss);
            }
            bf16x8 b0 = *reinterpret_cast<const bf16x8*>(&Ws[ lr        * LSTR + cl]);
            bf16x8 b1 = *reinterpret_cast<const bf16x8*>(&Ws[(16 + lr) * LSTR + cl]);
            bf16x8 b2 = *reinterpret_cast<const bf16x8*>(&Ws[(32 + lr) * LSTR + cl]);
            bf16x8 b3 = *reinterpret_cast<const bf16x8*>(&Ws[(48 + lr) * LSTR + cl]);
            acc[0] = __builtin_amdgcn_mfma_f32_16x16x32_bf16(af, b0, acc[0], 0, 0, 0);
            acc[1] = __builtin_amdgcn_mfma_f32_16x16x32_bf16(af, b1, acc[1], 0, 0, 0);
            acc[2] = __builtin_amdgcn_mfma_f32_16x16x32_bf16(af, b2, acc[2], 0, 0, 0);
            acc[3] = __builtin_amdgcn_mfma_f32_16x16x32_bf16(af, b3, acc[3], 0, 0, 0);
        }

        if (ch < 5) {
            __syncthreads();             // all waves done reading Ws & Gs[ch&1]
            GWRITE((ch + 1) & 1) WWRITED()
            __syncthreads();             // new chunk visible
        }
    }

    // ---- token norm: reduce the 4 lg-groups of the same token ----
    ss += __shfl_xor(ss, 16);
    ss += __shfl_xor(ss, 32);
    const float nrm = sqrtf(ss);
    const float inv = 1.0f / fmaxf(nrm, EPSF);

    // ---- logits + softmax over 64 regions ----
    float b_[4];
    #pragma unroll
    for (int rt = 0; rt < 4; ++rt) b_[rt] = conv_b[rt*16 + lr];

    float invT[4];
    #pragma unroll
    for (int reg = 0; reg < 4; ++reg) invT[reg] = __shfl(inv, (lg << 2) + reg);

    float lgt[4][4], mx[4];
    #pragma unroll
    for (int reg = 0; reg < 4; ++reg) {
        float m = -1e30f;
        #pragma unroll
        for (int rt = 0; rt < 4; ++rt) {
            lgt[rt][reg] = fmaf(acc[rt][reg], invT[reg], b_[rt]);
            m = fmaxf(m, lgt[rt][reg]);
        }
        mx[reg] = m;
    }
    #pragma unroll
    for (int msk = 1; msk < 16; msk <<= 1) {
        #pragma unroll
        for (int reg = 0; reg < 4; ++reg) mx[reg] = fmaxf(mx[reg], __shfl_xor(mx[reg], msk));
    }
    float ex[4][4], sm[4] = {0.f, 0.f, 0.f, 0.f};
    #pragma unroll
    for (int rt = 0; rt < 4; ++rt) {
        #pragma unroll
        for (int reg = 0; reg < 4; ++reg) {
            ex[rt][reg] = __expf(lgt[rt][reg] - mx[reg]);
            sm[reg] += ex[rt][reg];
        }
    }
    #pragma unroll
    for (int msk = 1; msk < 16; msk <<= 1) {
        #pragma unroll
        for (int reg = 0; reg < 4; ++reg) sm[reg] += __shfl_xor(sm[reg], msk);
    }

    float rsm[4];
    #pragma unroll
    for (int reg = 0; reg < 4; ++reg) {
        const bool vt = (t0w + (lg << 2) + reg) < TT;
        rsm[reg] = vt ? (1.0f / sm[reg]) : 0.f;
    }

    // ---- per-block partial asum: pa[rt] holds kr = rt*16+lr ----
    float pa[4];
    #pragma unroll
    for (int rt = 0; rt < 4; ++rt) {
        pa[rt] = ex[rt][0]*rsm[0] + ex[rt][1]*rsm[1] + ex[rt][2]*rsm[2] + ex[rt][3]*rsm[3];
        pa[rt] += __shfl_xor(pa[rt], 16);
        pa[rt] += __shfl_xor(pa[rt], 32);
    }
    if (lane < 16) {
        #pragma unroll
        for (int rt = 0; rt < 4; ++rt)
            asum_lds[w][rt*16 + lane] = pa[rt];
    }

    // ---- a' = softmax*inv_norm, transposed via wave-private LDS region.
    // Last chunk computed from Gs[1]; Abuf aliases Gs[0] (disjoint, safe).
    unsigned short* Abuf = &Gs[0][0] + (size_t)w * KR * 24;
    #pragma unroll
    for (int reg = 0; reg < 4; ++reg) {
        const int trow = (lg << 2) + reg;
        const float scale = invT[reg] * rsm[reg];
        #pragma unroll
        for (int rt = 0; rt < 4; ++rt)
            Abuf[(rt*16 + lr)*24 + trow] = f2bf(ex[rt][reg] * scale);
    }
    __syncthreads();

    if (tid < 64)
        ws_asum[(size_t)blockIdx.x * 64 + tid] =
            asum_lds[0][tid] + asum_lds[1][tid] + asum_lds[2][tid] + asum_lds[3][tid];

    {
        ushort8 r0 = *reinterpret_cast<const ushort8*>(&Abuf[lane * 24]);
        ushort8 r1 = *reinterpret_cast<const ushort8*>(&Abuf[lane * 24 + 8]);
        unsigned short* dst = ws_a + ((size_t)n * KR + lane) * TP + t0w;
        *reinterpret_cast<ushort8*>(dst)     = r0;
        *reinterpret_cast<ushort8*>(dst + 8) = r1;
    }
}

// ---------------------------------------------------------------------------
// Kernel 2: GEMM2 (VLAD): unchanged (proven R8). grid = n x 12 c-tiles.
// ---------------------------------------------------------------------------
#define LOADA(d0,d1,d2,d3,t0_)                                                   \
    d0 = *reinterpret_cast<const bf16x8*>(abase +           (size_t)(t0_));      \
    d1 = *reinterpret_cast<const bf16x8*>(abase + 16*TP +   (size_t)(t0_));      \
    d2 = *reinterpret_cast<const bf16x8*>(abase + 32*TP +   (size_t)(t0_));      \
    d3 = *reinterpret_cast<const bf16x8*>(abase + 48*TP +   (size_t)(t0_));

#define LOADB(d,t0_) do {                                                        \
    const int tb2_ = (t0_) + (lg << 3);                                          \
    if ((t0_) + 32 <= TT) {                                                      \
        _Pragma("unroll")                                                        \
        for (int j_ = 0; j_ < 8; ++j_)                                           \
            ((unsigned short*)&(d))[j_] = f2bf(gb[(size_t)(tb2_ + j_) * CCH]);   \
    } else {                                                                     \
        _Pragma("unroll")                                                        \
        for (int j_ = 0; j_ < 8; ++j_) {                                         \
            float v_ = (tb2_ + j_ < TT) ? gb[(size_t)(tb2_ + j_) * CCH] : 0.f;   \
            ((unsigned short*)&(d))[j_] = f2bf(v_);                              \
        }                                                                        \
    } } while (0)

__global__ __launch_bounds__(256, 4) void k_vlad(
    const float* __restrict__ grids,
    const unsigned short* __restrict__ ws_a,
    const float* __restrict__ ws_asum,
    const float* __restrict__ centroids,
    float* __restrict__ out)
{
    __shared__ float asum_s[64];

    const int tid  = threadIdx.x;
    const int lane = tid & 63;
    const int w    = tid >> 6;
    const int n    = blockIdx.x / 12;
    const int c0   = (blockIdx.x - n * 12) << 6;
    const int lr   = lane & 15;
    const int lg   = lane >> 4;

    if (tid < 64) {
        float s = 0.f;
        #pragma unroll
        for (int b = 0; b < 10; ++b)
            s += ws_asum[((size_t)n * 10 + b) * 64 + tid];
        asum_s[tid] = s;
    }
    __syncthreads();

    const int c = c0 + (w << 4) + lr;
    const unsigned short* abase = ws_a + ((size_t)n * KR + lr) * TP + (lg << 3);
    const float* gb = grids + (size_t)n * TT * CCH + c;

    f32x4 acc0 = {}, acc1 = {}, acc2 = {}, acc3 = {};
    bf16x8 a0, a1, a2, a3, b0;
    bf16x8 p0, p1, p2, p3, q0;

    LOADA(a0, a1, a2, a3, 0)
    LOADB(b0, 0);

    int t0 = 0;
    while (true) {
        int tn = t0 + 32;
        if (tn < TT) { LOADA(p0, p1, p2, p3, tn) LOADB(q0, tn); }
        acc0 = __builtin_amdgcn_mfma_f32_16x16x32_bf16(a0, b0, acc0, 0, 0, 0);
        acc1 = __builtin_amdgcn_mfma_f32_16x16x32_bf16(a1, b0, acc1, 0, 0, 0);
        acc2 = __builtin_amdgcn_mfma_f32_16x16x32_bf16(a2, b0, acc2, 0, 0, 0);
        acc3 = __builtin_amdgcn_mfma_f32_16x16x32_bf16(a3, b0, acc3, 0, 0, 0);
        t0 = tn;
        if (t0 >= TT) break;

        tn = t0 + 32;
        if (tn < TT) { LOADA(a0, a1, a2, a3, tn) LOADB(b0, tn); }
        acc0 = __builtin_amdgcn_mfma_f32_16x16x32_bf16(p0, q0, acc0, 0, 0, 0);
        acc1 = __builtin_amdgcn_mfma_f32_16x16x32_bf16(p1, q0, acc1, 0, 0, 0);
        acc2 = __builtin_amdgcn_mfma_f32_16x16x32_bf16(p2, q0, acc2, 0, 0, 0);
        acc3 = __builtin_amdgcn_mfma_f32_16x16x32_bf16(p3, q0, acc3, 0, 0, 0);
        t0 = tn;
        if (t0 >= TT) break;
    }

    #pragma unroll
    for (int reg = 0; reg < 4; ++reg) {
        {
            const int kr = 0*16 + (lg << 2) + reg;
            out[((size_t)n * KR + kr) * CCH + c] =
                acc0[reg] - asum_s[kr] * centroids[(size_t)kr * CCH + c];
        }
        {
            const int kr = 1*16 + (lg << 2) + reg;
            out[((size_t)n * KR + kr) * CCH + c] =
                acc1[reg] - asum_s[kr] * centroids[(size_t)kr * CCH + c];
        }
        {
            const int kr = 2*16 + (lg << 2) + reg;
            out[((size_t)n * KR + kr) * CCH + c] =
                acc2[reg] - asum_s[kr] * centroids[(size_t)kr * CCH + c];
        }
        {
            const int kr = 3*16 + (lg << 2) + reg;
            out[((size_t)n * KR + kr) * CCH + c] =
                acc3[reg] - asum_s[kr] * centroids[(size_t)kr * CCH + c];
        }
    }
}

// ---------------------------------------------------------------------------
// Kernel 3: 4 rows per 256-thr block; global L2 norm of 64 unit rows = 8.
// ---------------------------------------------------------------------------
__global__ __launch_bounds__(256) void kc_norm_kernel(float* __restrict__ out)
{
    const int tid = threadIdx.x;
    const int sub = tid >> 6;
    const int l   = tid & 63;
    float4* p = reinterpret_cast<float4*>(out) + ((size_t)blockIdx.x * 4 + sub) * 192;
    float4 v0 = p[l];
    float4 v1 = p[l + 64];
    float4 v2 = p[l + 128];
    float ss = v0.x*v0.x + v0.y*v0.y + v0.z*v0.z + v0.w*v0.w
             + v1.x*v1.x + v1.y*v1.y + v1.z*v1.z + v1.w*v1.w
             + v2.x*v2.x + v2.y*v2.y + v2.z*v2.z + v2.w*v2.w;
    #pragma unroll
    for (int m = 1; m < 64; m <<= 1) ss += __shfl_xor(ss, m);
    const float sc = 0.125f / fmaxf(sqrtf(ss), EPSF);
    v0.x*=sc; v0.y*=sc; v0.z*=sc; v0.w*=sc;
    v1.x*=sc; v1.y*=sc; v1.z*=sc; v1.w*=sc;
    v2.x*=sc; v2.y*=sc; v2.z*=sc; v2.w*=sc;
    p[l] = v0;
    p[l + 64] = v1;
    p[l + 128] = v2;
}

extern "C" void kernel_launch(void* const* d_in, const int* in_sizes, int n_in,
                              void* d_out, int out_size, void* d_ws, size_t ws_size,
                              hipStream_t stream)
{
    const float* grids     = (const float*)d_in[0];
    const float* conv_w    = (const float*)d_in[1];
    const float* conv_b    = (const float*)d_in[2];
    const float* centroids = (const float*)d_in[3];
    float* out = (float*)d_out;

    // ws layout (bytes):
    //   ws_a    [0,         5,242,880)   64*64*640 bf16
    //   ws_asum [5,242,880, 5,406,720)   640*64 f32
    //   ws_w    [5,406,720, 5,505,024)   64*768 bf16
    unsigned short* ws_a    = (unsigned short*)d_ws;
    float*          ws_asum = (float*)((char*)d_ws + 5242880);
    unsigned short* ws_w    = (unsigned short*)((char*)d_ws + 5406720);

    hipLaunchKernelGGL(k_prep, dim3(24), dim3(256), 0, stream,
                       conv_w, ws_w, ws_a);
    hipLaunchKernelGGL(k_logits, dim3(NB * 10), dim3(256), 0, stream,
                       grids, ws_w, conv_b, ws_a, ws_asum);
    hipLaunchKernelGGL(k_vlad, dim3(NB * 12), dim3(256), 0, stream,
                       grids, ws_a, ws_asum, centroids, out);
    hipLaunchKernelGGL(kc_norm_kernel, dim3(NB * KR / 4), dim3(256), 0, stream, out);
}

// Round 13
// 71.448 us; speedup vs baseline: 1.1033x; 1.1033x over previous
//
#include <hip/hip_runtime.h>
#include <hip/hip_bf16.h>
#include <math.h>

#define TT 577          // real tokens per n
#define TP 640          // padded tokens per n
#define CCH 768         // channels
#define KR 64           // regions
#define NB 64           // batch

typedef __attribute__((ext_vector_type(8))) short bf16x8;
typedef __attribute__((ext_vector_type(8))) unsigned short ushort8;
typedef __attribute__((ext_vector_type(4))) float f32x4;

static constexpr float EPSF = 1e-12f;

// float -> bf16 bits via HW conversion (RNE)
static __device__ inline unsigned short f2bf(float f) {
    return __bfloat16_as_ushort(__float2bfloat16(f));
}

// ---------------------------------------------------------------------------
// Kernel 1 (= R8 best-known + XCD-chunked swizzle): GEMM1 + norm + softmax +
// a' transpose + partial asum. Grid: 640 phys blocks; logical b swizzled so
// each XCD's 80 blocks cover a CONTIGUOUS 15.7-MB grids region (T1).
// ---------------------------------------------------------------------------
__global__ __launch_bounds__(256, 3) void k_logits(
    const float* __restrict__ grids,
    const float* __restrict__ conv_w,
    const float* __restrict__ conv_b,
    unsigned short* __restrict__ ws_a,
    float* __restrict__ ws_asum)
{
    __shared__ __align__(16) unsigned short Wl[2][KR * 136];   // 2 x 17.4 KB

    const int tid  = threadIdx.x;
    const int lane = tid & 63;
    const int w    = tid >> 6;
    // XCD-chunked bijective swizzle: 640 = 8 XCD x 80 chunk
    const int b    = (blockIdx.x & 7) * 80 + (blockIdx.x >> 3);
    const int n    = b / 10;
    const int tb   = (b - n * 10) << 6;
    const int t0w  = tb + (w << 4);

    const int lr = lane & 15;
    const int lg = lane >> 4;

    const int tokA = t0w + lr;
    const bool validA = (tokA < TT);
    const float* gsrc = grids + ((size_t)n * TT + tokA) * CCH + (lg << 3);

    float4 wreg[4][2];
    auto load_w = [&](int c0) {
        #pragma unroll
        for (int it = 0; it < 4; ++it) {
            int f = tid + (it << 8);
            int kr = f >> 4, c8 = (f & 15) << 3;
            const float* src = conv_w + (size_t)kr * CCH + c0 + c8;
            wreg[it][0] = *reinterpret_cast<const float4*>(src);
            wreg[it][1] = *reinterpret_cast<const float4*>(src + 4);
        }
    };
    auto store_w = [&](int buf) {
        #pragma unroll
        for (int it = 0; it < 4; ++it) {
            int f = tid + (it << 8);
            int kr = f >> 4, c8 = (f & 15) << 3;
            ushort8 o;
            o[0] = f2bf(wreg[it][0].x); o[1] = f2bf(wreg[it][0].y);
            o[2] = f2bf(wreg[it][0].z); o[3] = f2bf(wreg[it][0].w);
            o[4] = f2bf(wreg[it][1].x); o[5] = f2bf(wreg[it][1].y);
            o[6] = f2bf(wreg[it][1].z); o[7] = f2bf(wreg[it][1].w);
            *reinterpret_cast<ushort8*>(&Wl[buf][kr * 136 + c8]) = o;
        }
    };

    f32x4 acc[4] = {};
    float ss = 0.f;

    load_w(0);
    store_w(0);
    __syncthreads();

    for (int ch = 0; ch < 6; ++ch) {
        if (ch < 5) {
            load_w((ch + 1) << 7);
            store_w((ch + 1) & 1);
        }
        const int c0 = ch << 7;
        const unsigned short* Wb = Wl[ch & 1];

        #pragma unroll
        for (int s = 0; s < 4; ++s) {
            float a8[8];
            if (validA) {
                float4 u0 = *reinterpret_cast<const float4*>(gsrc + c0 + (s << 5));
                float4 u1 = *reinterpret_cast<const float4*>(gsrc + c0 + (s << 5) + 4);
                a8[0]=u0.x; a8[1]=u0.y; a8[2]=u0.z; a8[3]=u0.w;
                a8[4]=u1.x; a8[5]=u1.y; a8[6]=u1.z; a8[7]=u1.w;
            } else {
                #pragma unroll
                for (int j = 0; j < 8; ++j) a8[j] = 0.f;
            }
            bf16x8 afrag;
            #pragma unroll
            for (int j = 0; j < 8; ++j) {
                ss = fmaf(a8[j], a8[j], ss);
                ((unsigned short*)&afrag)[j] = f2bf(a8[j]);
            }
            const int cl = (s << 5) + (lg << 3);
            #pragma unroll
            for (int rt = 0; rt < 4; ++rt) {
                bf16x8 bfrag = *reinterpret_cast<const bf16x8*>(&Wb[(rt*16 + lr)*136 + cl]);
                acc[rt] = __builtin_amdgcn_mfma_f32_16x16x32_bf16(afrag, bfrag, acc[rt], 0, 0, 0);
            }
        }

        __syncthreads();
    }

    // ---- token norm: reduce the 4 lg-groups of the same token ----
    ss += __shfl_xor(ss, 16);
    ss += __shfl_xor(ss, 32);
    const float nrm = sqrtf(ss);
    const float inv = 1.0f / fmaxf(nrm, EPSF);

    // ---- logits + softmax over 64 regions ----
    float b_[4];
    #pragma unroll
    for (int rt = 0; rt < 4; ++rt) b_[rt] = conv_b[rt*16 + lr];

    float invT[4];
    #pragma unroll
    for (int reg = 0; reg < 4; ++reg) invT[reg] = __shfl(inv, (lg << 2) + reg);

    float lgt[4][4], mx[4];
    #pragma unroll
    for (int reg = 0; reg < 4; ++reg) {
        float m = -1e30f;
        #pragma unroll
        for (int rt = 0; rt < 4; ++rt) {
            lgt[rt][reg] = fmaf(acc[rt][reg], invT[reg], b_[rt]);
            m = fmaxf(m, lgt[rt][reg]);
        }
        mx[reg] = m;
    }
    #pragma unroll
    for (int msk = 1; msk < 16; msk <<= 1) {
        #pragma unroll
        for (int reg = 0; reg < 4; ++reg) mx[reg] = fmaxf(mx[reg], __shfl_xor(mx[reg], msk));
    }
    float ex[4][4], sm[4] = {0.f, 0.f, 0.f, 0.f};
    #pragma unroll
    for (int rt = 0; rt < 4; ++rt) {
        #pragma unroll
        for (int reg = 0; reg < 4; ++reg) {
            ex[rt][reg] = __expf(lgt[rt][reg] - mx[reg]);
            sm[reg] += ex[rt][reg];
        }
    }
    #pragma unroll
    for (int msk = 1; msk < 16; msk <<= 1) {
        #pragma unroll
        for (int reg = 0; reg < 4; ++reg) sm[reg] += __shfl_xor(sm[reg], msk);
    }

    float rsm[4];
    #pragma unroll
    for (int reg = 0; reg < 4; ++reg) {
        const bool vt = (t0w + (lg << 2) + reg) < TT;
        rsm[reg] = vt ? (1.0f / sm[reg]) : 0.f;
    }

    // ---- per-block partial asum: pa[rt] holds kr = rt*16+lr ----
    float pa[4];
    #pragma unroll
    for (int rt = 0; rt < 4; ++rt) {
        pa[rt] = ex[rt][0]*rsm[0] + ex[rt][1]*rsm[1] + ex[rt][2]*rsm[2] + ex[rt][3]*rsm[3];
        pa[rt] += __shfl_xor(pa[rt], 16);
        pa[rt] += __shfl_xor(pa[rt], 32);
    }
    float* asum_lds = reinterpret_cast<float*>(&Wl[1][0]);   // [4 waves][64 kr]
    if (lane < 16) {
        #pragma unroll
        for (int rt = 0; rt < 4; ++rt)
            asum_lds[(w << 6) + rt*16 + lane] = pa[rt];
    }

    // ---- a' = softmax * inv_norm, transposed via LDS (aliased on Wl[0]) ----
    unsigned short* Abuf = &Wl[0][0] + (size_t)w * KR * 24;
    #pragma unroll
    for (int reg = 0; reg < 4; ++reg) {
        const int trow = (lg << 2) + reg;
        const float scale = invT[reg] * rsm[reg];
        #pragma unroll
        for (int rt = 0; rt < 4; ++rt)
            Abuf[(rt*16 + lr)*24 + trow] = f2bf(ex[rt][reg] * scale);
    }
    __syncthreads();

    if (tid < 64)
        ws_asum[(size_t)b * 64 + tid] =
            asum_lds[tid] + asum_lds[64 + tid] + asum_lds[128 + tid] + asum_lds[192 + tid];

    {
        ushort8 r0 = *reinterpret_cast<const ushort8*>(&Abuf[lane * 24]);
        ushort8 r1 = *reinterpret_cast<const ushort8*>(&Abuf[lane * 24 + 8]);
        unsigned short* dst = ws_a + ((size_t)n * KR + lane) * TP + t0w;
        *reinterpret_cast<ushort8*>(dst)     = r0;
        *reinterpret_cast<ushort8*>(dst + 8) = r1;
    }
}

// ---------------------------------------------------------------------------
// Kernel 2 (= R8 + XCD swizzle): all 12 c-tile blocks of an n land on ONE
// XCD -> grids slice shared in that XCD's L2. 768 = 8 x 96.
// ---------------------------------------------------------------------------
#define LOADA(d0,d1,d2,d3,t0_)                                                   \
    d0 = *reinterpret_cast<const bf16x8*>(abase +           (size_t)(t0_));      \
    d1 = *reinterpret_cast<const bf16x8*>(abase + 16*TP +   (size_t)(t0_));      \
    d2 = *reinterpret_cast<const bf16x8*>(abase + 32*TP +   (size_t)(t0_));      \
    d3 = *reinterpret_cast<const bf16x8*>(abase + 48*TP +   (size_t)(t0_));

#define LOADB(d,t0_) do {                                                        \
    const int tb2_ = (t0_) + (lg << 3);                                          \
    if ((t0_) + 32 <= TT) {                                                      \
        _Pragma("unroll")                                                        \
        for (int j_ = 0; j_ < 8; ++j_)                                           \
            ((unsigned short*)&(d))[j_] = f2bf(gb[(size_t)(tb2_ + j_) * CCH]);   \
    } else {                                                                     \
        _Pragma("unroll")                                                        \
        for (int j_ = 0; j_ < 8; ++j_) {                                         \
            float v_ = (tb2_ + j_ < TT) ? gb[(size_t)(tb2_ + j_) * CCH] : 0.f;   \
            ((unsigned short*)&(d))[j_] = f2bf(v_);                              \
        }                                                                        \
    } } while (0)

__global__ __launch_bounds__(256, 4) void k_vlad(
    const float* __restrict__ grids,
    const unsigned short* __restrict__ ws_a,
    const float* __restrict__ ws_asum,
    const float* __restrict__ centroids,
    float* __restrict__ out)
{
    __shared__ float asum_s[64];

    const int tid  = threadIdx.x;
    const int lane = tid & 63;
    const int w    = tid >> 6;
    // XCD-chunked bijective swizzle: 768 = 8 XCD x 96 chunk
    const int b    = (blockIdx.x & 7) * 96 + (blockIdx.x >> 3);
    const int n    = b / 12;
    const int c0   = (b - n * 12) << 6;
    const int lr   = lane & 15;
    const int lg   = lane >> 4;

    if (tid < 64) {
        float s = 0.f;
        #pragma unroll
        for (int bb = 0; bb < 10; ++bb)
            s += ws_asum[((size_t)n * 10 + bb) * 64 + tid];
        asum_s[tid] = s;
    }
    __syncthreads();

    const int c = c0 + (w << 4) + lr;
    const unsigned short* abase = ws_a + ((size_t)n * KR + lr) * TP + (lg << 3);
    const float* gb = grids + (size_t)n * TT * CCH + c;

    f32x4 acc0 = {}, acc1 = {}, acc2 = {}, acc3 = {};
    bf16x8 a0, a1, a2, a3, b0;
    bf16x8 p0, p1, p2, p3, q0;

    LOADA(a0, a1, a2, a3, 0)
    LOADB(b0, 0);

    int t0 = 0;
    while (true) {
        int tn = t0 + 32;
        if (tn < TT) { LOADA(p0, p1, p2, p3, tn) LOADB(q0, tn); }
        acc0 = __builtin_amdgcn_mfma_f32_16x16x32_bf16(a0, b0, acc0, 0, 0, 0);
        acc1 = __builtin_amdgcn_mfma_f32_16x16x32_bf16(a1, b0, acc1, 0, 0, 0);
        acc2 = __builtin_amdgcn_mfma_f32_16x16x32_bf16(a2, b0, acc2, 0, 0, 0);
        acc3 = __builtin_amdgcn_mfma_f32_16x16x32_bf16(a3, b0, acc3, 0, 0, 0);
        t0 = tn;
        if (t0 >= TT) break;

        tn = t0 + 32;
        if (tn < TT) { LOADA(a0, a1, a2, a3, tn) LOADB(b0, tn); }
        acc0 = __builtin_amdgcn_mfma_f32_16x16x32_bf16(p0, q0, acc0, 0, 0, 0);
        acc1 = __builtin_amdgcn_mfma_f32_16x16x32_bf16(p1, q0, acc1, 0, 0, 0);
        acc2 = __builtin_amdgcn_mfma_f32_16x16x32_bf16(p2, q0, acc2, 0, 0, 0);
        acc3 = __builtin_amdgcn_mfma_f32_16x16x32_bf16(p3, q0, acc3, 0, 0, 0);
        t0 = tn;
        if (t0 >= TT) break;
    }

    #pragma unroll
    for (int reg = 0; reg < 4; ++reg) {
        {
            const int kr = 0*16 + (lg << 2) + reg;
            out[((size_t)n * KR + kr) * CCH + c] =
                acc0[reg] - asum_s[kr] * centroids[(size_t)kr * CCH + c];
        }
        {
            const int kr = 1*16 + (lg << 2) + reg;
            out[((size_t)n * KR + kr) * CCH + c] =
                acc1[reg] - asum_s[kr] * centroids[(size_t)kr * CCH + c];
        }
        {
            const int kr = 2*16 + (lg << 2) + reg;
            out[((size_t)n * KR + kr) * CCH + c] =
                acc2[reg] - asum_s[kr] * centroids[(size_t)kr * CCH + c];
        }
        {
            const int kr = 3*16 + (lg << 2) + reg;
            out[((size_t)n * KR + kr) * CCH + c] =
                acc3[reg] - asum_s[kr] * centroids[(size_t)kr * CCH + c];
        }
    }
}

// ---------------------------------------------------------------------------
// Kernel 3: 4 rows per 256-thr block; global L2 norm of 64 unit rows = 8.
// ---------------------------------------------------------------------------
__global__ __launch_bounds__(256) void kc_norm_kernel(float* __restrict__ out)
{
    const int tid = threadIdx.x;
    const int sub = tid >> 6;
    const int l   = tid & 63;
    float4* p = reinterpret_cast<float4*>(out) + ((size_t)blockIdx.x * 4 + sub) * 192;
    float4 v0 = p[l];
    float4 v1 = p[l + 64];
    float4 v2 = p[l + 128];
    float ss = v0.x*v0.x + v0.y*v0.y + v0.z*v0.z + v0.w*v0.w
             + v1.x*v1.x + v1.y*v1.y + v1.z*v1.z + v1.w*v1.w
             + v2.x*v2.x + v2.y*v2.y + v2.z*v2.z + v2.w*v2.w;
    #pragma unroll
    for (int m = 1; m < 64; m <<= 1) ss += __shfl_xor(ss, m);
    const float sc = 0.125f / fmaxf(sqrtf(ss), EPSF);
    v0.x*=sc; v0.y*=sc; v0.z*=sc; v0.w*=sc;
    v1.x*=sc; v1.y*=sc; v1.z*=sc; v1.w*=sc;
    v2.x*=sc; v2.y*=sc; v2.z*=sc; v2.w*=sc;
    p[l] = v0;
    p[l + 64] = v1;
    p[l + 128] = v2;
}

extern "C" void kernel_launch(void* const* d_in, const int* in_sizes, int n_in,
                              void* d_out, int out_size, void* d_ws, size_t ws_size,
                              hipStream_t stream)
{
    const float* grids     = (const float*)d_in[0];
    const float* conv_w    = (const float*)d_in[1];
    const float* conv_b    = (const float*)d_in[2];
    const float* centroids = (const float*)d_in[3];
    float* out = (float*)d_out;

    // ws layout (bytes):
    //   ws_a    [0,         5,242,880)   64*64*640 bf16
    //   ws_asum [5,242,880, 5,406,720)   640*64 f32
    unsigned short* ws_a    = (unsigned short*)d_ws;
    float*          ws_asum = (float*)((char*)d_ws + 5242880);

    hipLaunchKernelGGL(k_logits, dim3(NB * 10), dim3(256), 0, stream,
                       grids, conv_w, conv_b, ws_a, ws_asum);
    hipLaunchKernelGGL(k_vlad, dim3(NB * 12), dim3(256), 0, stream,
                       grids, ws_a, ws_asum, centroids, out);
    hipLaunchKernelGGL(kc_norm_kernel, dim3(NB * KR / 4), dim3(256), 0, stream, out);
}